// Round 11
// baseline (184.545 us; speedup 1.0000x reference)
//
#include <hip/hip_runtime.h>

// B=32, S=2048, I=128, H=512, O=64, R=1, ALPHA=0.1  (rank-1 scalar-state RNN)
// DIAGNOSTIC ROUND: main kernel (mode 0) is byte-identical in structure to
// round-10 (116 us, passed). Three probe launches (mode 1/2/3) stop after
// ph1/ph2/ph3 and dump to d_ws -- their rocprof dispatch durations give the
// per-phase split by subtraction. After 3 null micro-opts and 2 magnitude
// mispredictions, the phase model needs ground truth (ablate-before-optimize).
//   ph1: u[t] = x[t,:].irc for t in [r0-128,r0+256); global_load_lds (16B),
//        counted vmcnt, 3-slot pipeline, per-wave stripes (no syncthreads)
//   ph2: 8 waves x 38-t V-chunks, 86 uniform steps (48 warm-up), scalar VSTEP
//   ph3: w rows [0,304) = relu(V*rp+u*ip) @ W^T via 16x16x32 bf16 MFMA -> sw
//   ph4: y-scan, 8 waves x 32 outputs, 48-step warm-up (w rows t<0 are zero)

#define B_ 32
#define S_ 2048
#define I_ 128
#define H_ 512
#define O_ 64

typedef __attribute__((ext_vector_type(8))) short bf16x8;
typedef __attribute__((ext_vector_type(4))) float f32x4;

__device__ __forceinline__ unsigned short f2bf(float f) {
  unsigned int b = __float_as_uint(f);
  b += 0x7FFFu + ((b >> 16) & 1u);
  return (unsigned short)(b >> 16);
}
__device__ __forceinline__ float bf2f(unsigned short s) {
  return __uint_as_float(((unsigned)s) << 16);
}
__device__ __forceinline__ unsigned pack_bf(float lo, float hi) {
  unsigned a = (__float_as_uint(lo) + 0x8000u) >> 16;
  unsigned b = (__float_as_uint(hi) + 0x8000u) & 0xFFFF0000u;
  return a | b;
}

// DPP add via update_dpp (verified r0-r10). CTRL: 0x121/2/4/8 = row_ror 1/2/4/8
// (every lane -> its 16-lane row sum); 0x142 = row_bcast15; 0x143 = row_bcast31.
// After ror x4 + bcast15 + bcast31: lane63 = full 64-lane sum.
#define DPP_ADD(s, CTRL) \
  s += __int_as_float(__builtin_amdgcn_update_dpp(0, __float_as_int(s), CTRL, 0xF, 0xF, true))

#define RL(s, L) __int_as_float(__builtin_amdgcn_readlane(__float_as_int(s), (L)))

// async global->LDS, 16B/lane; LDS dest = uniform base + lane*16 (HW rule)
__device__ __forceinline__ void gload16(const void* g, void* l) {
  __builtin_amdgcn_global_load_lds(
      (const __attribute__((address_space(1))) unsigned int*)g,
      (__attribute__((address_space(3))) unsigned int*)l, 16, 0, 0);
}
#define WAITVM(N) asm volatile("s_waitcnt vmcnt(" #N ")" ::: "memory")
#define SCHEDB() __builtin_amdgcn_sched_barrier(0)

// LDS layout (bytes): su[480]f | sV[384]f | srp[512]f | sip[512]f |
//   sw[320*64]ush | xs: 3 x 32768 x-slots (ph1) aliased by sBF[32768]ush (ph3)
#define OFF_SU 0
#define OFF_SV 1920
#define OFF_RP 3456
#define OFF_IP 5504
#define OFF_SW 7552
#define OFF_XS 48512
#define SMEM_BYTES 146816

// sw bank-swizzle (verified r0-r10): row stride 128 B; XOR col bits 4-5 with
// (row>>2)&3 (== quad in ph3) spreads quads across banks.
__device__ __forceinline__ int swz(int row, int col) {
  return row * 64 + (col ^ ((((unsigned)row >> 2) & 3) << 4));
}

__global__ __launch_bounds__(512, 1) void k_fused(
    const float* __restrict__ x, const float* __restrict__ ipj,
    const float* __restrict__ irc, const float* __restrict__ rpj,
    const float* __restrict__ rrc, const float* __restrict__ Wr,
    const float* __restrict__ bias, float* __restrict__ out,
    float* __restrict__ wsp, int mode) {
  extern __shared__ __align__(16) char smem[];
  float* su = (float*)(smem + OFF_SU);
  float* sV = (float*)(smem + OFF_SV);
  float* srp = (float*)(smem + OFF_RP);
  float* sip = (float*)(smem + OFF_IP);
  unsigned short* sw = (unsigned short*)(smem + OFF_SW);
  unsigned short* sBF = (unsigned short*)(smem + OFF_XS);
  float* xsf = (float*)(smem + OFF_XS);

  const int tid = threadIdx.x;
  const int wv = tid >> 6;      // 0..7
  const int lane = tid & 63;
  const int b = blockIdx.x >> 3;
  const int g = blockIdx.x & 7;
  const int r0 = g * 256;

  // ---- top preloads (oldest in VMEM FIFO; retired by ph1's counted waits) ----
  // ph1 dot: lane handles row (wv*8 + (lane>>3)), col segs (lane&7)*4 + 32i
  f32x4 cv0 = *(const f32x4*)(irc + 4 * (lane & 7));
  f32x4 cv1 = *(const f32x4*)(irc + 4 * (lane & 7) + 32);
  f32x4 cv2 = *(const f32x4*)(irc + 4 * (lane & 7) + 64);
  f32x4 cv3 = *(const f32x4*)(irc + 4 * (lane & 7) + 96);
  // ph2 per-lane params, h = lane + 64k; 0.1 folded into rrv (r10-verified)
  float rpv[8], ipv[8], rrv[8];
  #pragma unroll
  for (int k = 0; k < 8; k++) {
    int h = lane + 64 * k;
    rpv[k] = rpj[h]; ipv[k] = ipj[h]; rrv[k] = 0.1f * rrc[h];
  }
  // zero pads: su[384..480) (suB tail lanes read it), sV[304..384)
  if (tid < 96) su[384 + tid] = 0.f;
  if (tid < 80) sV[304 + tid] = 0.f;

  // ---------------- Phase 1: x window [r0-128,r0+256) -> su via gll pipeline.
  // 6 chunks of 64 rows (32 KB). Wave stages its own rows [wv*8,+8) (4 glls,
  // 1 KB each) into slot c%3 and consumes only those -> no syncthreads needed.
  // ORDER INVARIANT (r6 bug): ISSUE(c+3) reuses slot c%3 -> must be emitted
  // AFTER COMPUTE(c)'s ds_reads. sched_barrier(0) pins compile order.
#define ISSUE(c) do { \
    int tc_ = r0 - 128 + (c) * 64 + wv * 8; if (tc_ < 0) tc_ = 0; \
    const float* gs_ = x + ((size_t)b * S_ + tc_) * I_ + lane * 4; \
    char* ld_ = (char*)xsf + ((c) % 3) * 32768 + wv * 4096; \
    gload16(gs_,       ld_); \
    gload16(gs_ + 256, ld_ + 1024); \
    gload16(gs_ + 512, ld_ + 2048); \
    gload16(gs_ + 768, ld_ + 3072); \
  } while (0)

#define COMPUTE(c) do { \
    const float* bp_ = xsf + ((c) % 3) * 8192 + (wv * 8 + (lane >> 3)) * 128 + (lane & 7) * 4; \
    f32x4 x0_ = *(const f32x4*)(bp_); \
    f32x4 x1_ = *(const f32x4*)(bp_ + 32); \
    f32x4 x2_ = *(const f32x4*)(bp_ + 64); \
    f32x4 x3_ = *(const f32x4*)(bp_ + 96); \
    float p0_ = x0_[0] * cv0[0], p1_ = x0_[1] * cv0[1]; \
    float p2_ = x0_[2] * cv0[2], p3_ = x0_[3] * cv0[3]; \
    p0_ = fmaf(x1_[0], cv1[0], p0_); p1_ = fmaf(x1_[1], cv1[1], p1_); \
    p2_ = fmaf(x1_[2], cv1[2], p2_); p3_ = fmaf(x1_[3], cv1[3], p3_); \
    p0_ = fmaf(x2_[0], cv2[0], p0_); p1_ = fmaf(x2_[1], cv2[1], p1_); \
    p2_ = fmaf(x2_[2], cv2[2], p2_); p3_ = fmaf(x2_[3], cv2[3], p3_); \
    p0_ = fmaf(x3_[0], cv3[0], p0_); p1_ = fmaf(x3_[1], cv3[1], p1_); \
    p2_ = fmaf(x3_[2], cv3[2], p2_); p3_ = fmaf(x3_[3], cv3[3], p3_); \
    float s_ = (p0_ + p1_) + (p2_ + p3_); \
    DPP_ADD(s_, 0x121); DPP_ADD(s_, 0x122); DPP_ADD(s_, 0x124); \
    float mask_ = (r0 - 128 + (c) * 64 >= 0) ? 1.f : 0.f; \
    if ((lane & 7) == 7) su[(c) * 64 + wv * 8 + (lane >> 3)] = s_ * mask_; \
  } while (0)

  ISSUE(0); ISSUE(1); ISSUE(2);
  WAITVM(8); COMPUTE(0); SCHEDB(); ISSUE(3);
  WAITVM(8); COMPUTE(1); SCHEDB(); ISSUE(4);
  WAITVM(8); COMPUTE(2); SCHEDB(); ISSUE(5);
  WAITVM(8); COMPUTE(3);
  WAITVM(4); COMPUTE(4);
  WAITVM(0); COMPUTE(5);
  __syncthreads();   // su complete; x slots dead

  // ---- PROBE mode 1: stop after ph1; dump su ----
  if (mode == 1) {
    if (tid < 480) wsp[(size_t)blockIdx.x * 480 + tid] = su[tid];
    return;
  }

  // ---- su window for this wave's chain -> 2 VGPRs (readlane broadcast).
  float suA = su[32 + wv * 38 + lane];
  float suB = su[32 + wv * 38 + 64 + lane];

  // ---- W preload to registers (static-indexed); converted after ph2 so the
  // L2 loads hide under the scan. Frag map (verified r0-r10):
  // sBF[((kt*4+ot)*64+l2)*8+j] = bf(W[(ot*16+(l2&15))*H + kt*32+(l2>>4)*8+j])
  float4 wA0, wB0, wA1, wB1, wA2, wB2, wA3, wB3;
  float4 wA4, wB4, wA5, wB5, wA6, wB6, wA7, wB7;
#define WLOAD(m, A, Bv) do { \
    int seg_ = tid + 512 * (m); \
    int l2_ = seg_ & 63, ot_ = (seg_ >> 6) & 3, kt_ = seg_ >> 8; \
    const float4* wp_ = (const float4*)(Wr + (size_t)(ot_ * 16 + (l2_ & 15)) * H_ + kt_ * 32 + (l2_ >> 4) * 8); \
    A = wp_[0]; Bv = wp_[1]; \
  } while (0)
  WLOAD(0, wA0, wB0); WLOAD(1, wA1, wB1); WLOAD(2, wA2, wB2); WLOAD(3, wA3, wB3);
  WLOAD(4, wA4, wB4); WLOAD(5, wA5, wB5); WLOAD(6, wA6, wB6); WLOAD(7, wA7, wB7);
  // 512 threads -> each thread stages exactly ONE srp/sip element (r4 lesson)
  float rpa = rpj[tid];
  float ipa = ipj[tid];

  // ---------------- Phase 2: V-scan. Wave wv produces sV rows [wv*38,+38);
  // 86 uniform steps (48 warm-up). ut from registers via readlane.
#define VSTEP(UT) do { \
    float ut_ = (UT); \
    float q0 = fmaxf(fmaf(v, rpv[0], ut_ * ipv[0]), 0.f) * rrv[0]; \
    float q1 = fmaxf(fmaf(v, rpv[1], ut_ * ipv[1]), 0.f) * rrv[1]; \
    float q2 = fmaxf(fmaf(v, rpv[2], ut_ * ipv[2]), 0.f) * rrv[2]; \
    float q3 = fmaxf(fmaf(v, rpv[3], ut_ * ipv[3]), 0.f) * rrv[3]; \
    float q4 = fmaxf(fmaf(v, rpv[4], ut_ * ipv[4]), 0.f) * rrv[4]; \
    float q5 = fmaxf(fmaf(v, rpv[5], ut_ * ipv[5]), 0.f) * rrv[5]; \
    float q6 = fmaxf(fmaf(v, rpv[6], ut_ * ipv[6]), 0.f) * rrv[6]; \
    float q7 = fmaxf(fmaf(v, rpv[7], ut_ * ipv[7]), 0.f) * rrv[7]; \
    float s_ = ((q0 + q1) + (q2 + q3)) + ((q4 + q5) + (q6 + q7)); \
    DPP_ADD(s_, 0x121); DPP_ADD(s_, 0x122); DPP_ADD(s_, 0x124); DPP_ADD(s_, 0x128); \
    DPP_ADD(s_, 0x142); DPP_ADD(s_, 0x143); \
    float tot_ = RL(s_, 63); \
    v = fmaf(0.9f, v, tot_); \
  } while (0)
  {
    float v = 0.f;
    int base = wv * 38;
    #pragma unroll 8
    for (int i = 0; i < 48; i++) VSTEP(RL(suA, i));            // warm-up
    #pragma unroll 8
    for (int k = 0; k < 16; k++) {                             // real, su in A
      if (lane == 0) sV[base + k] = v;                         // v entering step
      VSTEP(RL(suA, 48 + k));
    }
    #pragma unroll 2
    for (int k = 16; k < 38; k++) {                            // real, su in B
      if (lane == 0) sV[base + k] = v;
      VSTEP(RL(suB, k - 16));
    }
  }

  // ---- PROBE mode 2: stop after ph2; dump sV ----
  if (mode == 2) {
    __syncthreads();
    if (tid < 304) wsp[200000 + (size_t)blockIdx.x * 304 + tid] = sV[tid];
    return;
  }

  // ---- convert W regs -> sBF (aliases dead x slots), stage srp/sip ----
#define WPACK(m, A, Bv) do { \
    int seg_ = tid + 512 * (m); \
    uint4 pk_; \
    pk_.x = (unsigned)f2bf(A.x) | ((unsigned)f2bf(A.y) << 16); \
    pk_.y = (unsigned)f2bf(A.z) | ((unsigned)f2bf(A.w) << 16); \
    pk_.z = (unsigned)f2bf(Bv.x) | ((unsigned)f2bf(Bv.y) << 16); \
    pk_.w = (unsigned)f2bf(Bv.z) | ((unsigned)f2bf(Bv.w) << 16); \
    *(uint4*)(sBF + seg_ * 8) = pk_; \
  } while (0)
  WPACK(0, wA0, wB0); WPACK(1, wA1, wB1); WPACK(2, wA2, wB2); WPACK(3, wA3, wB3);
  WPACK(4, wA4, wB4); WPACK(5, wA5, wB5); WPACK(6, wA6, wB6); WPACK(7, wA7, wB7);
  srp[tid] = rpa;
  sip[tid] = ipa;
  __syncthreads();   // sV + sBF + srp/sip ready

  // ---------------- Phase 3: w rows [0,304) via MFMA; 3 m-tiles/wave (mt<19).
  // sV row k <-> t = r0-48+k; matching u is su[80+k].
  {
    int tl = lane & 15, quad = lane >> 4;
    float Vr0 = sV[(wv * 3 + 0) * 16 + tl], ur0 = su[80 + (wv * 3 + 0) * 16 + tl];
    float Vr1 = sV[(wv * 3 + 1) * 16 + tl], ur1 = su[80 + (wv * 3 + 1) * 16 + tl];
    float Vr2 = sV[(wv * 3 + 2) * 16 + tl], ur2 = su[80 + (wv * 3 + 2) * 16 + tl];
    f32x4 acc[3][4] = {};  // [m][ot]
    #pragma unroll 4
    for (int kt = 0; kt < 16; kt++) {
      int hbase = kt * 32 + quad * 8;
      f32x4 rp4a = *(const f32x4*)(srp + hbase);
      f32x4 rp4b = *(const f32x4*)(srp + hbase + 4);
      f32x4 ip4a = *(const f32x4*)(sip + hbase);
      f32x4 ip4b = *(const f32x4*)(sip + hbase + 4);
      bf16x8 bfr0 = *(const bf16x8*)(sBF + (((kt * 4 + 0) * 64 + lane) << 3));
      bf16x8 bfr1 = *(const bf16x8*)(sBF + (((kt * 4 + 1) * 64 + lane) << 3));
      bf16x8 bfr2 = *(const bf16x8*)(sBF + (((kt * 4 + 2) * 64 + lane) << 3));
      bf16x8 bfr3 = *(const bf16x8*)(sBF + (((kt * 4 + 3) * 64 + lane) << 3));
      #pragma unroll
      for (int m = 0; m < 3; m++) {
        float Vm = m == 0 ? Vr0 : (m == 1 ? Vr1 : Vr2);
        float um = m == 0 ? ur0 : (m == 1 ? ur1 : ur2);
        float q[8];
        #pragma unroll
        for (int j = 0; j < 4; j++) {
          q[j]     = fmaxf(fmaf(Vm, rp4a[j], um * ip4a[j]), 0.f);
          q[4 + j] = fmaxf(fmaf(Vm, rp4b[j], um * ip4b[j]), 0.f);
        }
        union { bf16x8 v; unsigned w[4]; } a;
        #pragma unroll
        for (int j = 0; j < 4; j++) a.w[j] = pack_bf(q[2 * j], q[2 * j + 1]);
        acc[m][0] = __builtin_amdgcn_mfma_f32_16x16x32_bf16(a.v, bfr0, acc[m][0], 0, 0, 0);
        acc[m][1] = __builtin_amdgcn_mfma_f32_16x16x32_bf16(a.v, bfr1, acc[m][1], 0, 0, 0);
        acc[m][2] = __builtin_amdgcn_mfma_f32_16x16x32_bf16(a.v, bfr2, acc[m][2], 0, 0, 0);
        acc[m][3] = __builtin_amdgcn_mfma_f32_16x16x32_bf16(a.v, bfr3, acc[m][3], 0, 0, 0);
      }
    }
    // C/D layout: col = ot*16 + tl (o), row-in-tile = quad*4 + r (t offset)
    #pragma unroll
    for (int m = 0; m < 3; m++) {
      int mt = wv * 3 + m;
      if (mt < 19) {
        int rbase = mt * 16 + quad * 4;
        #pragma unroll
        for (int r = 0; r < 4; r++) {
          #pragma unroll
          for (int ot = 0; ot < 4; ot++)
            sw[swz(rbase + r, ot * 16 + tl)] = f2bf(acc[m][ot][r]);
        }
      }
    }
  }
  __syncthreads();

  // ---- PROBE mode 3: stop after ph3; dump sw token ----
  if (mode == 3) {
    ((unsigned short*)(wsp + 400000))[(size_t)blockIdx.x * 512 + tid] = sw[tid];
    return;
  }

  // ---------------- Phase 4: y-scan. Wave wv owns outputs [r0+wv*32,+32);
  // scans sw rows [wv*32,+80) = 48 warm + 32 real (rows with t<0 are zero).
  {
    float y = 0.f;
    float bo = bias[lane];
    int k0 = wv * 32;
    float* ob = out + ((size_t)(b * S_ + r0 + k0)) * O_ + lane;
    #pragma unroll 8
    for (int i = 0; i < 48; i++)
      y = fmaf(0.9f, y, 0.1f * bf2f(sw[swz(k0 + i, lane)]));
    #pragma unroll 4
    for (int i = 0; i < 32; i++) {
      y = fmaf(0.9f, y, 0.1f * bf2f(sw[swz(k0 + 48 + i, lane)]));
      ob[(size_t)i * O_] = y + bo;
    }
  }
}

extern "C" void kernel_launch(void* const* d_in, const int* in_sizes, int n_in,
                              void* d_out, int out_size, void* d_ws, size_t ws_size,
                              hipStream_t stream) {
  const float* x   = (const float*)d_in[0];
  const float* ipj = (const float*)d_in[1];
  const float* irc = (const float*)d_in[2];
  const float* rpj = (const float*)d_in[3];
  const float* rrc = (const float*)d_in[4];
  const float* Wr  = (const float*)d_in[5];
  const float* br  = (const float*)d_in[6];
  float* out = (float*)d_out;
  float* ws  = (float*)d_ws;

  static bool s_init = false;
  if (!s_init) {
    hipFuncSetAttribute((const void*)k_fused,
                        hipFuncAttributeMaxDynamicSharedMemorySize, SMEM_BYTES);
    s_init = true;
  }
  // Real run (mode 0) first -> correct `out`. Then phase probes (write d_ws
  // only): mode1 = ph1, mode2 = ph1+ph2, mode3 = ph1+ph2+ph3. Their rocprof
  // dispatch durations give the per-phase split by subtraction.
  k_fused<<<dim3(256), dim3(512), SMEM_BYTES, stream>>>(x, ipj, irc, rpj, rrc,
                                                        Wr, br, out, ws, 0);
  k_fused<<<dim3(256), dim3(512), SMEM_BYTES, stream>>>(x, ipj, irc, rpj, rrc,
                                                        Wr, br, out, ws, 1);
  k_fused<<<dim3(256), dim3(512), SMEM_BYTES, stream>>>(x, ipj, irc, rpj, rrc,
                                                        Wr, br, out, ws, 2);
  k_fused<<<dim3(256), dim3(512), SMEM_BYTES, stream>>>(x, ipj, irc, rpj, rrc,
                                                        Wr, br, out, ws, 3);
}